// Round 1
// baseline (784.207 us; speedup 1.0000x reference)
//
#include <hip/hip_runtime.h>
#include <math.h>

#define BSZ 4
#define SEQ 2048
#define DIM 1024
#define HID 4096
#define MTOT (BSZ * SEQ)   // 8192 tokens
#define TM 128
#define TN 128
#define KB 32
#define NHT (HID / TN)     // 32 h-tiles
#define EPSF 1e-9f

// ---------------------------------------------------------------------------
// Kernel A: fused gate GEMM. partial[ht][token] = sum_{h in tile ht} relu(hidden@W1 + b1) * W2
// fp32 vector GEMM, 128x128 tile, 8x8 micro-tile, KB=32 LDS staging.
// ---------------------------------------------------------------------------
__global__ __launch_bounds__(256, 2)
void gate_gemm(const float* __restrict__ A, const float* __restrict__ W1,
               const float* __restrict__ b1, const float* __restrict__ W2,
               float* __restrict__ partial) {
  __shared__ float As[KB][TM + 4];   // [k][m], padded stride 132 (16B-aligned, fewer write conflicts)
  __shared__ float Bs[KB][TN];       // [k][n]
  const int ht = blockIdx.x, mt = blockIdx.y;
  const int t = threadIdx.x;
  const int tx = t & 15, ty = t >> 4;
  const float* Ab = A + (size_t)(mt * TM) * DIM;
  const float* Wb = W1 + ht * TN;

  float acc[8][8];
#pragma unroll
  for (int i = 0; i < 8; ++i)
#pragma unroll
    for (int j = 0; j < 8; ++j) acc[i][j] = 0.f;

  const int kq = (t & 7) * 4;    // k sub-offset for A load
  const int mrow = t >> 3;       // 0..31
  const int bcol = (t & 31) * 4; // col quad for B load
  const int brow = t >> 5;       // 0..7

  for (int k0 = 0; k0 < DIM; k0 += KB) {
#pragma unroll
    for (int p = 0; p < 4; ++p) {
      int m = mrow + p * 32;
      float4 v = *(const float4*)(Ab + (size_t)m * DIM + k0 + kq);
      As[kq + 0][m] = v.x;
      As[kq + 1][m] = v.y;
      As[kq + 2][m] = v.z;
      As[kq + 3][m] = v.w;
    }
#pragma unroll
    for (int p = 0; p < 4; ++p) {
      int k = brow + p * 8;
      *(float4*)&Bs[k][bcol] = *(const float4*)(Wb + (size_t)(k0 + k) * HID + bcol);
    }
    __syncthreads();
#pragma unroll
    for (int k = 0; k < KB; ++k) {
      float a[8], bb[8];
      *(float4*)&a[0]  = *(const float4*)&As[k][ty * 8];
      *(float4*)&a[4]  = *(const float4*)&As[k][ty * 8 + 4];
      *(float4*)&bb[0] = *(const float4*)&Bs[k][tx * 8];
      *(float4*)&bb[4] = *(const float4*)&Bs[k][tx * 8 + 4];
#pragma unroll
      for (int i = 0; i < 8; ++i)
#pragma unroll
        for (int j = 0; j < 8; ++j)
          acc[i][j] = fmaf(a[i], bb[j], acc[i][j]);
    }
    __syncthreads();
  }

  // epilogue: relu + weighted reduce over the 8 h-columns, then reduce across tx
  const int hbase = ht * TN + tx * 8;
  float w2v[8], b1v[8];
#pragma unroll
  for (int j = 0; j < 8; ++j) { w2v[j] = W2[hbase + j]; b1v[j] = b1[hbase + j]; }
  float part[8];
#pragma unroll
  for (int i = 0; i < 8; ++i) {
    float s = 0.f;
#pragma unroll
    for (int j = 0; j < 8; ++j) {
      float h = acc[i][j] + b1v[j];
      s += fmaxf(h, 0.f) * w2v[j];
    }
    part[i] = s;
  }
  // threads sharing the same 8 token-rows are the 16 consecutive lanes (tx 0..15)
#pragma unroll
  for (int off = 1; off < 16; off <<= 1)
#pragma unroll
    for (int i = 0; i < 8; ++i)
      part[i] += __shfl_xor(part[i], off);
  if (tx == 0) {
    int m0 = mt * TM + ty * 8;
#pragma unroll
    for (int i = 0; i < 8; ++i)
      partial[(size_t)ht * MTOT + m0 + i] = part[i];
  }
}

// ---------------------------------------------------------------------------
// Kernel B: per-row -> logits, hard boundaries, forced last-real boundary,
// exclusive scan, boundary positions, counts, short_mask.
// ---------------------------------------------------------------------------
__global__ void boundary_scan(const float* __restrict__ partial,
                              const float* __restrict__ mask,
                              const float* __restrict__ noise,
                              const float* __restrict__ b2,
                              int* __restrict__ bpos, int* __restrict__ counts,
                              int* __restrict__ lengths,
                              float* __restrict__ shortmask) {
  const int b = blockIdx.x;
  const int t = threadIdx.x;
  __shared__ float hardS[SEQ];
  __shared__ float red[256];
  const float bias2 = b2[0];

  float msum = 0.f;
  for (int s = t; s < SEQ; s += 256) {
    float lg = bias2;
#pragma unroll
    for (int h = 0; h < NHT; ++h) lg += partial[(size_t)h * MTOT + b * SEQ + s];
    float u = noise[b * SEQ + s];
    float lgt = logf(u) - log1pf(-u);   // logistic noise
    float m = mask[b * SEQ + s];
    float hard = ((lg + lgt) > 0.f) ? 1.f : 0.f;  // sigmoid(x)>0.5 <=> x>0
    hardS[s] = hard * m;
    msum += m;
  }
  red[t] = msum;
  __syncthreads();
  for (int off = 128; off > 0; off >>= 1) {
    if (t < off) red[t] += red[t + off];
    __syncthreads();
  }
  int L = (int)(red[0] + 0.5f);  // valid length (mask is left-packed ones)
  __syncthreads();
  if (t == 0) {
    if (L < SEQ) hardS[L - 1] = fmaxf(hardS[L - 1], 1.f);  // forced boundary on last real token
    lengths[b] = L;
  }
  __syncthreads();

  // block-wide exclusive scan: each thread owns tokens [t*8, t*8+8)
  float loc[8];
  float run = 0.f;
#pragma unroll
  for (int i = 0; i < 8; ++i) { loc[i] = hardS[t * 8 + i]; run += loc[i]; }
  red[t] = run;
  __syncthreads();
  for (int off = 1; off < 256; off <<= 1) {
    float v = (t >= off) ? red[t - off] : 0.f;
    __syncthreads();
    red[t] += v;
    __syncthreads();
  }
  float base = red[t] - run;  // exclusive prefix for this thread's chunk
  float cntF = red[255];
  int cnt = (int)(cntF + 0.5f);

  float pre = base;
#pragma unroll
  for (int i = 0; i < 8; ++i) {
    if (loc[i] > 0.5f) {
      int rank = (int)(pre + 0.5f);     // hh1 of this boundary token
      bpos[b * SEQ + rank] = t * 8 + i; // position of (rank+1)-th boundary
    }
    pre += loc[i];
  }
  if (t == 0) counts[b] = cnt;
  for (int s = t; s < SEQ; s += 256)
    shortmask[b * SEQ + s] = (s < cnt) ? 1.f : 0.f;
}

// ---------------------------------------------------------------------------
// Kernel C: per-(b, seg) mean pooling over the contiguous token range.
// Segments g < cnt here; g == cnt (leftover+padding, possibly long) handled by
// the 2-pass tail kernels; g > cnt -> zeros.
// ---------------------------------------------------------------------------
__global__ void pool_seg(const float* __restrict__ hidden,
                         const int* __restrict__ bpos,
                         const int* __restrict__ counts,
                         float* __restrict__ pooled) {
  const int g = blockIdx.x, b = blockIdx.y;
  const int t = threadIdx.x;
  const int cnt = counts[b];
  float4 acc = {0.f, 0.f, 0.f, 0.f};
  float* outp = pooled + ((size_t)(b * SEQ + g)) * DIM + t * 4;
  if (g > cnt) { *(float4*)outp = acc; return; }
  if (g == cnt) return;  // written by pool_tail_final
  int start = (g == 0) ? 0 : bpos[b * SEQ + g - 1] + 1;
  int end = bpos[b * SEQ + g] + 1;
  const float* hb = hidden + ((size_t)b * SEQ) * DIM + t * 4;
  for (int l = start; l < end; ++l) {
    float4 v = *(const float4*)(hb + (size_t)l * DIM);
    acc.x += v.x; acc.y += v.y; acc.z += v.z; acc.w += v.w;
  }
  float inv = 1.f / ((float)(end - start) + EPSF);
  acc.x *= inv; acc.y *= inv; acc.z *= inv; acc.w *= inv;
  *(float4*)outp = acc;
}

// Kernel C2: partial sums of the leftover segment (tokens after last boundary,
// including padding), split over 16 chunks for parallelism.
__global__ void pool_tail_partial(const float* __restrict__ hidden,
                                  const int* __restrict__ bpos,
                                  const int* __restrict__ counts,
                                  float* __restrict__ tailpart) {
  const int c = blockIdx.x;  // 0..15
  const int b = blockIdx.y;
  const int t = threadIdx.x;
  int cnt = counts[b];
  int start = (cnt == 0) ? 0 : bpos[b * SEQ + cnt - 1] + 1;
  int n = SEQ - start;
  int clen = (n + 15) / 16;
  int s0 = start + c * clen;
  int s1 = s0 + clen; if (s1 > SEQ) s1 = SEQ;
  float4 acc = {0.f, 0.f, 0.f, 0.f};
  const float* hb = hidden + ((size_t)b * SEQ) * DIM + t * 4;
  for (int l = s0; l < s1; ++l) {
    float4 v = *(const float4*)(hb + (size_t)l * DIM);
    acc.x += v.x; acc.y += v.y; acc.z += v.z; acc.w += v.w;
  }
  *(float4*)(tailpart + ((size_t)(b * 16 + c)) * DIM + t * 4) = acc;
}

// Kernel C3: combine tail partials -> pooled[b][cnt]
__global__ void pool_tail_final(const int* __restrict__ bpos,
                                const int* __restrict__ counts,
                                const float* __restrict__ tailpart,
                                float* __restrict__ pooled) {
  const int b = blockIdx.x;
  const int t = threadIdx.x;
  int cnt = counts[b];
  if (cnt >= SEQ) return;  // no output slot for leftover segment
  int start = (cnt == 0) ? 0 : bpos[b * SEQ + cnt - 1] + 1;
  float4 acc = {0.f, 0.f, 0.f, 0.f};
  for (int c = 0; c < 16; ++c) {
    float4 v = *(const float4*)(tailpart + ((size_t)(b * 16 + c)) * DIM + t * 4);
    acc.x += v.x; acc.y += v.y; acc.z += v.z; acc.w += v.w;
  }
  float inv = 1.f / ((float)(SEQ - start) + EPSF);
  acc.x *= inv; acc.y *= inv; acc.z *= inv; acc.w *= inv;
  *(float4*)(pooled + ((size_t)(b * SEQ + cnt)) * DIM + t * 4) = acc;
}

// ---------------------------------------------------------------------------
// Kernel D: binomial loss (double precision lgamma), num_b, total
// ---------------------------------------------------------------------------
__global__ void loss_kernel(const int* __restrict__ counts,
                            const int* __restrict__ lengths,
                            float* __restrict__ outScalars) {
  if (threadIdx.x != 0 || blockIdx.x != 0) return;
  double num_b = 0.0, total = 0.0;
  for (int b = 0; b < BSZ; ++b) { num_b += (double)counts[b]; total += (double)lengths[b]; }
  double lp = lgamma(total + 1.0) - lgamma(num_b + 1.0) - lgamma(total - num_b + 1.0)
            + num_b * log(0.2) + (total - num_b) * log(0.8);
  double loss = -lp / total;
  outScalars[0] = (float)loss;
  outScalars[1] = (float)num_b;
  outScalars[2] = (float)total;
}

// ---------------------------------------------------------------------------
extern "C" void kernel_launch(void* const* d_in, const int* in_sizes, int n_in,
                              void* d_out, int out_size, void* d_ws, size_t ws_size,
                              hipStream_t stream) {
  const float* hidden = (const float*)d_in[0];
  const float* mask   = (const float*)d_in[1];
  const float* noise  = (const float*)d_in[2];
  const float* W1     = (const float*)d_in[3];
  const float* b1     = (const float*)d_in[4];
  const float* W2     = (const float*)d_in[5];
  const float* b2     = (const float*)d_in[6];

  float* out = (float*)d_out;
  float* pooled = out;                                  // [B,S,D]
  float* scalars = out + (size_t)BSZ * SEQ * DIM;       // loss, num_b, total
  float* shortmask = scalars + 3;                       // [B,S]

  char* ws = (char*)d_ws;
  float* partial = (float*)ws;                                       // 32*8192 f32 = 1 MB
  size_t off = (size_t)NHT * MTOT * sizeof(float);
  int* bpos = (int*)(ws + off);                                      // [B,S] int = 32 KB
  off += (size_t)BSZ * SEQ * sizeof(int);
  int* counts = (int*)(ws + off);                                    // [B]
  off += BSZ * sizeof(int);
  int* lengths = (int*)(ws + off);                                   // [B]
  off += BSZ * sizeof(int);
  off = (off + 15) & ~(size_t)15;
  float* tailpart = (float*)(ws + off);                              // [B,16,D] f32 = 256 KB

  gate_gemm<<<dim3(NHT, MTOT / TM), 256, 0, stream>>>(hidden, W1, b1, W2, partial);
  boundary_scan<<<BSZ, 256, 0, stream>>>(partial, mask, noise, b2,
                                         bpos, counts, lengths, shortmask);
  pool_tail_partial<<<dim3(16, BSZ), 256, 0, stream>>>(hidden, bpos, counts, tailpart);
  pool_seg<<<dim3(SEQ, BSZ), 256, 0, stream>>>(hidden, bpos, counts, pooled);
  pool_tail_final<<<BSZ, 256, 0, stream>>>(bpos, counts, tailpart, pooled);
  loss_kernel<<<1, 1, 0, stream>>>(counts, lengths, scalars);
}

// Round 2
// 321.031 us; speedup vs baseline: 2.4428x; 2.4428x over previous
//
#include <hip/hip_runtime.h>
#include <math.h>

#define BSZ 4
#define SEQ 2048
#define DIM 1024
#define HID 4096
#define MTOT (BSZ * SEQ)   // 8192 tokens
#define NHB 64             // partial h-blocks (32 ht-tiles * 2 wn)
#define EPSF 1e-9f

#define BM 128
#define BN 128
#define BKF 32             // K elems per staging iter
#define KITERS (DIM / BKF) // 32
#define LOSCALE 2048.0f
#define INV_LOSCALE (1.0f / 2048.0f)

typedef _Float16 f16;
typedef _Float16 f16x4 __attribute__((ext_vector_type(4)));
typedef _Float16 f16x8 __attribute__((ext_vector_type(8)));
typedef float f32x16 __attribute__((ext_vector_type(16)));

__device__ __forceinline__ void gl16(const f16* g, f16* l) {
  __builtin_amdgcn_global_load_lds(
      (const __attribute__((address_space(1))) void*)g,
      (__attribute__((address_space(3))) void*)l, 16, 0, 0);
}

// ---------------------------------------------------------------------------
// Split hidden -> fp16 hi/lo (lo scaled by 2048). [8192][1024]
// ---------------------------------------------------------------------------
__global__ void split_a(const float* __restrict__ in, f16* __restrict__ hi,
                        f16* __restrict__ lo) {
  int i = blockIdx.x * 256 + threadIdx.x;   // 4 elems per thread
  float4 v = ((const float4*)in)[i];
  f16x4 h, l;
  h.x = (f16)v.x; h.y = (f16)v.y; h.z = (f16)v.z; h.w = (f16)v.w;
  l.x = (f16)((v.x - (float)h.x) * LOSCALE);
  l.y = (f16)((v.y - (float)h.y) * LOSCALE);
  l.z = (f16)((v.z - (float)h.z) * LOSCALE);
  l.w = (f16)((v.w - (float)h.w) * LOSCALE);
  ((f16x4*)hi)[i] = h;
  ((f16x4*)lo)[i] = l;
}

// ---------------------------------------------------------------------------
// Split + transpose W1 [1024][4096] -> W1T hi/lo fp16 [4096][1024]
// ---------------------------------------------------------------------------
__global__ void split_w1t(const float* __restrict__ w1, f16* __restrict__ hi,
                          f16* __restrict__ lo) {
  __shared__ float tile[32][36];
  const int k0 = blockIdx.x * 32;  // 32 k-tiles
  const int h0 = blockIdx.y * 32;  // 128 h-tiles
  const int t = threadIdx.x;
  {
    int kk = t >> 3, hq = (t & 7) * 4;
    float4 v = *(const float4*)&w1[(size_t)(k0 + kk) * HID + h0 + hq];
    tile[kk][hq + 0] = v.x; tile[kk][hq + 1] = v.y;
    tile[kk][hq + 2] = v.z; tile[kk][hq + 3] = v.w;
  }
  __syncthreads();
  int hh = t >> 3, kq = (t & 7) * 4;
  f16x4 H, L;
#pragma unroll
  for (int j = 0; j < 4; ++j) {
    float x = tile[kq + j][hh];
    f16 xh = (f16)x;
    H[j] = xh;
    L[j] = (f16)((x - (float)xh) * LOSCALE);
  }
  *(f16x4*)&hi[(size_t)(h0 + hh) * DIM + k0 + kq] = H;
  *(f16x4*)&lo[(size_t)(h0 + hh) * DIM + k0 + kq] = L;
}

// ---------------------------------------------------------------------------
// Gate GEMM: partial[ht*2+wn][token] = sum_{h in 64-col slice} relu(A@W1+b1)*W2
// fp16-split MFMA (32x32x16), 128x128 tile, BK=32, dbuf, global_load_lds.
// ---------------------------------------------------------------------------
__global__ __launch_bounds__(256, 2)
void gate_gemm(const f16* __restrict__ Ahi, const f16* __restrict__ Alo,
               const f16* __restrict__ Whi, const f16* __restrict__ Wlo,
               const float* __restrict__ b1, const float* __restrict__ W2,
               float* __restrict__ partial) {
  __shared__ f16 sA[2][2][BM][BKF];  // [buf][hi/lo][row][k]  32 KB
  __shared__ f16 sB[2][2][BN][BKF];  //                        32 KB

  // XCD-bijective swizzle (2048 % 8 == 0) + 4x4 supertile for L2 reuse
  const int bid = blockIdx.x;
  const int wg = (bid & 7) * 256 + (bid >> 3);
  const int st = wg >> 4, q = wg & 15;
  const int mt = (st >> 3) * 4 + (q >> 2);  // 0..63
  const int ht = (st & 7) * 4 + (q & 3);    // 0..31
  const int m0 = mt * BM, h0 = ht * BN;

  const int t = threadIdx.x;
  const int lane = t & 63, wid = t >> 6;
  const int wm = wid >> 1, wn = wid & 1;

  f32x16 accM[2][2], accC[2][2];
#pragma unroll
  for (int a = 0; a < 2; ++a)
#pragma unroll
    for (int b = 0; b < 2; ++b)
#pragma unroll
      for (int e = 0; e < 16; ++e) { accM[a][b][e] = 0.f; accC[a][b][e] = 0.f; }

  // staging: 512 16B-slots per tile-half; wave covers slots [(wid*2+i)*64 + lane]
  // source k-slot pre-swizzled (sl = sp ^ (r&3)) so LDS stays linear (rule #21)
#define STAGE(buf, kt)                                                        \
  {                                                                           \
    const int k0s = (kt) * BKF;                                               \
    _Pragma("unroll") for (int i = 0; i < 2; ++i) {                           \
      int sig = ((wid * 2 + i) << 6) + lane;                                  \
      int r = sig >> 2, sp = sig & 3;                                         \
      int sl = sp ^ (r & 3);                                                  \
      size_t goA = (size_t)(m0 + r) * DIM + k0s + sl * 8;                     \
      size_t goB = (size_t)(h0 + r) * DIM + k0s + sl * 8;                     \
      f16* dstbase = ((wid * 2 + i) << 6) * 8 + (f16*)nullptr;                \
      (void)dstbase;                                                          \
      int ho = ((wid * 2 + i) << 6) * 8;                                      \
      gl16(Ahi + goA, &sA[buf][0][0][0] + ho);                                \
      gl16(Alo + goA, &sA[buf][1][0][0] + ho);                                \
      gl16(Whi + goB, &sB[buf][0][0][0] + ho);                                \
      gl16(Wlo + goB, &sB[buf][1][0][0] + ho);                                \
    }                                                                         \
  }

  STAGE(0, 0);
  __syncthreads();

  const int rowl = lane & 31, kb = lane >> 5;

  for (int kt = 0; kt < KITERS; ++kt) {
    const int buf = kt & 1;
    if (kt + 1 < KITERS) STAGE(buf ^ 1, kt + 1);
#pragma unroll
    for (int ks = 0; ks < 2; ++ks) {
      f16x8 ah[2], al[2], bh[2], bl[2];
      const int sl = ks * 2 + kb;
#pragma unroll
      for (int f = 0; f < 2; ++f) {
        int ra = wm * 64 + f * 32 + rowl;
        int spa = (sl ^ (ra & 3)) * 8;
        ah[f] = *(const f16x8*)&sA[buf][0][ra][spa];
        al[f] = *(const f16x8*)&sA[buf][1][ra][spa];
        int rb = wn * 64 + f * 32 + rowl;
        int spb = (sl ^ (rb & 3)) * 8;
        bh[f] = *(const f16x8*)&sB[buf][0][rb][spb];
        bl[f] = *(const f16x8*)&sB[buf][1][rb][spb];
      }
#pragma unroll
      for (int fm = 0; fm < 2; ++fm)
#pragma unroll
        for (int fn = 0; fn < 2; ++fn) {
          accM[fm][fn] = __builtin_amdgcn_mfma_f32_32x32x16_f16(
              ah[fm], bh[fn], accM[fm][fn], 0, 0, 0);
          accC[fm][fn] = __builtin_amdgcn_mfma_f32_32x32x16_f16(
              ah[fm], bl[fn], accC[fm][fn], 0, 0, 0);
          accC[fm][fn] = __builtin_amdgcn_mfma_f32_32x32x16_f16(
              al[fm], bh[fn], accC[fm][fn], 0, 0, 0);
        }
    }
    __syncthreads();
  }

  // epilogue: relu(h + b1) * W2, reduce over the 32 h-cols per frag + fn pair
  float b1v[2], w2v[2];
#pragma unroll
  for (int fn = 0; fn < 2; ++fn) {
    int h = h0 + wn * 64 + fn * 32 + rowl;
    b1v[fn] = b1[h];
    w2v[fn] = W2[h];
  }
  float red[2][16];
#pragma unroll
  for (int fm = 0; fm < 2; ++fm)
#pragma unroll
    for (int r = 0; r < 16; ++r) {
      float v0 = accM[fm][0][r] + accC[fm][0][r] * INV_LOSCALE + b1v[0];
      float v1 = accM[fm][1][r] + accC[fm][1][r] * INV_LOSCALE + b1v[1];
      red[fm][r] = fmaxf(v0, 0.f) * w2v[0] + fmaxf(v1, 0.f) * w2v[1];
    }
#pragma unroll
  for (int off = 1; off <= 16; off <<= 1)
#pragma unroll
    for (int fm = 0; fm < 2; ++fm)
#pragma unroll
      for (int r = 0; r < 16; ++r)
        red[fm][r] += __shfl_xor(red[fm][r], off);
  if (rowl == 0) {
    const int hb = ht * 2 + wn;
#pragma unroll
    for (int fm = 0; fm < 2; ++fm)
#pragma unroll
      for (int r = 0; r < 16; ++r) {
        int token = m0 + wm * 64 + fm * 32 + (r & 3) + 8 * (r >> 2) + 4 * kb;
        partial[(size_t)hb * MTOT + token] = red[fm][r];
      }
  }
}

// ---------------------------------------------------------------------------
// Kernel B: logits -> hard boundaries -> scan -> positions/counts/short_mask
// ---------------------------------------------------------------------------
__global__ void boundary_scan(const float* __restrict__ partial,
                              const float* __restrict__ mask,
                              const float* __restrict__ noise,
                              const float* __restrict__ b2,
                              int* __restrict__ bpos, int* __restrict__ counts,
                              int* __restrict__ lengths,
                              float* __restrict__ shortmask) {
  const int b = blockIdx.x;
  const int t = threadIdx.x;
  __shared__ float hardS[SEQ];
  __shared__ float red[256];
  const float bias2 = b2[0];

  float msum = 0.f;
  for (int s = t; s < SEQ; s += 256) {
    float lg = bias2;
#pragma unroll
    for (int h = 0; h < NHB; ++h) lg += partial[(size_t)h * MTOT + b * SEQ + s];
    float u = noise[b * SEQ + s];
    float lgt = logf(u) - log1pf(-u);
    float m = mask[b * SEQ + s];
    float hard = ((lg + lgt) > 0.f) ? 1.f : 0.f;
    hardS[s] = hard * m;
    msum += m;
  }
  red[t] = msum;
  __syncthreads();
  for (int off = 128; off > 0; off >>= 1) {
    if (t < off) red[t] += red[t + off];
    __syncthreads();
  }
  int L = (int)(red[0] + 0.5f);
  __syncthreads();
  if (t == 0) {
    if (L < SEQ) hardS[L - 1] = fmaxf(hardS[L - 1], 1.f);
    lengths[b] = L;
  }
  __syncthreads();

  float loc[8];
  float run = 0.f;
#pragma unroll
  for (int i = 0; i < 8; ++i) { loc[i] = hardS[t * 8 + i]; run += loc[i]; }
  red[t] = run;
  __syncthreads();
  for (int off = 1; off < 256; off <<= 1) {
    float v = (t >= off) ? red[t - off] : 0.f;
    __syncthreads();
    red[t] += v;
    __syncthreads();
  }
  float base = red[t] - run;
  int cnt = (int)(red[255] + 0.5f);

  float pre = base;
#pragma unroll
  for (int i = 0; i < 8; ++i) {
    if (loc[i] > 0.5f) {
      int rank = (int)(pre + 0.5f);
      bpos[b * SEQ + rank] = t * 8 + i;
    }
    pre += loc[i];
  }
  if (t == 0) counts[b] = cnt;
  for (int s = t; s < SEQ; s += 256)
    shortmask[b * SEQ + s] = (s < cnt) ? 1.f : 0.f;
}

// ---------------------------------------------------------------------------
// Pooling kernels (unchanged from round 1)
// ---------------------------------------------------------------------------
__global__ void pool_seg(const float* __restrict__ hidden,
                         const int* __restrict__ bpos,
                         const int* __restrict__ counts,
                         float* __restrict__ pooled) {
  const int g = blockIdx.x, b = blockIdx.y;
  const int t = threadIdx.x;
  const int cnt = counts[b];
  float4 acc = {0.f, 0.f, 0.f, 0.f};
  float* outp = pooled + ((size_t)(b * SEQ + g)) * DIM + t * 4;
  if (g > cnt) { *(float4*)outp = acc; return; }
  if (g == cnt) return;
  int start = (g == 0) ? 0 : bpos[b * SEQ + g - 1] + 1;
  int end = bpos[b * SEQ + g] + 1;
  const float* hb = hidden + ((size_t)b * SEQ) * DIM + t * 4;
  for (int l = start; l < end; ++l) {
    float4 v = *(const float4*)(hb + (size_t)l * DIM);
    acc.x += v.x; acc.y += v.y; acc.z += v.z; acc.w += v.w;
  }
  float inv = 1.f / ((float)(end - start) + EPSF);
  acc.x *= inv; acc.y *= inv; acc.z *= inv; acc.w *= inv;
  *(float4*)outp = acc;
}

__global__ void pool_tail_partial(const float* __restrict__ hidden,
                                  const int* __restrict__ bpos,
                                  const int* __restrict__ counts,
                                  float* __restrict__ tailpart) {
  const int c = blockIdx.x;
  const int b = blockIdx.y;
  const int t = threadIdx.x;
  int cnt = counts[b];
  int start = (cnt == 0) ? 0 : bpos[b * SEQ + cnt - 1] + 1;
  int n = SEQ - start;
  int clen = (n + 15) / 16;
  int s0 = start + c * clen;
  int s1 = s0 + clen; if (s1 > SEQ) s1 = SEQ;
  float4 acc = {0.f, 0.f, 0.f, 0.f};
  const float* hb = hidden + ((size_t)b * SEQ) * DIM + t * 4;
  for (int l = s0; l < s1; ++l) {
    float4 v = *(const float4*)(hb + (size_t)l * DIM);
    acc.x += v.x; acc.y += v.y; acc.z += v.z; acc.w += v.w;
  }
  *(float4*)(tailpart + ((size_t)(b * 16 + c)) * DIM + t * 4) = acc;
}

__global__ void pool_tail_final(const int* __restrict__ bpos,
                                const int* __restrict__ counts,
                                const float* __restrict__ tailpart,
                                float* __restrict__ pooled) {
  const int b = blockIdx.x;
  const int t = threadIdx.x;
  int cnt = counts[b];
  if (cnt >= SEQ) return;
  int start = (cnt == 0) ? 0 : bpos[b * SEQ + cnt - 1] + 1;
  float4 acc = {0.f, 0.f, 0.f, 0.f};
  for (int c = 0; c < 16; ++c) {
    float4 v = *(const float4*)(tailpart + ((size_t)(b * 16 + c)) * DIM + t * 4);
    acc.x += v.x; acc.y += v.y; acc.z += v.z; acc.w += v.w;
  }
  float inv = 1.f / ((float)(SEQ - start) + EPSF);
  acc.x *= inv; acc.y *= inv; acc.z *= inv; acc.w *= inv;
  *(float4*)(pooled + ((size_t)(b * SEQ + cnt)) * DIM + t * 4) = acc;
}

__global__ void loss_kernel(const int* __restrict__ counts,
                            const int* __restrict__ lengths,
                            float* __restrict__ outScalars) {
  if (threadIdx.x != 0 || blockIdx.x != 0) return;
  double num_b = 0.0, total = 0.0;
  for (int b = 0; b < BSZ; ++b) { num_b += (double)counts[b]; total += (double)lengths[b]; }
  double lp = lgamma(total + 1.0) - lgamma(num_b + 1.0) - lgamma(total - num_b + 1.0)
            + num_b * log(0.2) + (total - num_b) * log(0.8);
  outScalars[0] = (float)(-lp / total);
  outScalars[1] = (float)num_b;
  outScalars[2] = (float)total;
}

// ---------------------------------------------------------------------------
extern "C" void kernel_launch(void* const* d_in, const int* in_sizes, int n_in,
                              void* d_out, int out_size, void* d_ws, size_t ws_size,
                              hipStream_t stream) {
  const float* hidden = (const float*)d_in[0];
  const float* mask   = (const float*)d_in[1];
  const float* noise  = (const float*)d_in[2];
  const float* W1     = (const float*)d_in[3];
  const float* b1     = (const float*)d_in[4];
  const float* W2     = (const float*)d_in[5];
  const float* b2     = (const float*)d_in[6];

  float* out = (float*)d_out;
  float* pooled = out;
  float* scalars = out + (size_t)BSZ * SEQ * DIM;
  float* shortmask = scalars + 3;

  char* ws = (char*)d_ws;
  size_t off = 0;
  float* partial = (float*)(ws + off); off += (size_t)NHB * MTOT * sizeof(float); // 2 MB
  f16* Ahi = (f16*)(ws + off); off += (size_t)MTOT * DIM * sizeof(f16);           // 16 MB
  f16* Alo = (f16*)(ws + off); off += (size_t)MTOT * DIM * sizeof(f16);           // 16 MB
  f16* Whi = (f16*)(ws + off); off += (size_t)HID * DIM * sizeof(f16);            // 8 MB
  f16* Wlo = (f16*)(ws + off); off += (size_t)HID * DIM * sizeof(f16);            // 8 MB
  int* bpos = (int*)(ws + off); off += (size_t)BSZ * SEQ * sizeof(int);
  int* counts = (int*)(ws + off); off += 16 * sizeof(int);
  int* lengths = (int*)(ws + off); off += 16 * sizeof(int);
  off = (off + 255) & ~(size_t)255;
  float* tailpart = (float*)(ws + off);                                           // 256 KB

  split_a<<<MTOT * DIM / 4 / 256, 256, 0, stream>>>(hidden, Ahi, Alo);
  split_w1t<<<dim3(DIM / 32, HID / 32), 256, 0, stream>>>(W1, Whi, Wlo);
  gate_gemm<<<(MTOT / BM) * (HID / BN), 256, 0, stream>>>(Ahi, Alo, Whi, Wlo,
                                                          b1, W2, partial);
  boundary_scan<<<BSZ, 256, 0, stream>>>(partial, mask, noise, b2,
                                         bpos, counts, lengths, shortmask);
  pool_tail_partial<<<dim3(16, BSZ), 256, 0, stream>>>(hidden, bpos, counts, tailpart);
  pool_seg<<<dim3(SEQ, BSZ), 256, 0, stream>>>(hidden, bpos, counts, pooled);
  pool_tail_final<<<BSZ, 256, 0, stream>>>(bpos, counts, tailpart, pooled);
  loss_kernel<<<1, 1, 0, stream>>>(counts, lengths, scalars);
}

// Round 3
// 285.435 us; speedup vs baseline: 2.7474x; 1.1247x over previous
//
#include <hip/hip_runtime.h>
#include <math.h>

#define BSZ 4
#define SEQ 2048
#define DIM 1024
#define HID 4096
#define MTOT (BSZ * SEQ)   // 8192 tokens
#define NHB 64             // partial h-blocks (32 ht-tiles * 2 wn)
#define EPSF 1e-9f

#define BM 128
#define BN 128
#define BKF 32             // K elems per staging iter
#define KITERS (DIM / BKF) // 32
#define LOSCALE 2048.0f
#define INV_LOSCALE (1.0f / 2048.0f)

typedef _Float16 f16;
typedef _Float16 f16x4 __attribute__((ext_vector_type(4)));
typedef _Float16 f16x8 __attribute__((ext_vector_type(8)));
typedef float f32x16 __attribute__((ext_vector_type(16)));

__device__ __forceinline__ void gl16(const f16* g, f16* l) {
  __builtin_amdgcn_global_load_lds(
      (const __attribute__((address_space(1))) void*)g,
      (__attribute__((address_space(3))) void*)l, 16, 0, 0);
}

// ---------------------------------------------------------------------------
// Split hidden -> fp16 hi/lo (lo scaled by 2048). [8192][1024]
// ---------------------------------------------------------------------------
__global__ void split_a(const float* __restrict__ in, f16* __restrict__ hi,
                        f16* __restrict__ lo) {
  int i = blockIdx.x * 256 + threadIdx.x;   // 4 elems per thread
  float4 v = ((const float4*)in)[i];
  f16x4 h, l;
  h.x = (f16)v.x; h.y = (f16)v.y; h.z = (f16)v.z; h.w = (f16)v.w;
  l.x = (f16)((v.x - (float)h.x) * LOSCALE);
  l.y = (f16)((v.y - (float)h.y) * LOSCALE);
  l.z = (f16)((v.z - (float)h.z) * LOSCALE);
  l.w = (f16)((v.w - (float)h.w) * LOSCALE);
  ((f16x4*)hi)[i] = h;
  ((f16x4*)lo)[i] = l;
}

// ---------------------------------------------------------------------------
// Split + transpose W1 [1024][4096] -> W1T hi/lo fp16 [4096][1024]
// ---------------------------------------------------------------------------
__global__ void split_w1t(const float* __restrict__ w1, f16* __restrict__ hi,
                          f16* __restrict__ lo) {
  __shared__ float tile[32][36];
  const int k0 = blockIdx.x * 32;  // 32 k-tiles
  const int h0 = blockIdx.y * 32;  // 128 h-tiles
  const int t = threadIdx.x;
  {
    int kk = t >> 3, hq = (t & 7) * 4;
    float4 v = *(const float4*)&w1[(size_t)(k0 + kk) * HID + h0 + hq];
    tile[kk][hq + 0] = v.x; tile[kk][hq + 1] = v.y;
    tile[kk][hq + 2] = v.z; tile[kk][hq + 3] = v.w;
  }
  __syncthreads();
  int hh = t >> 3, kq = (t & 7) * 4;
  f16x4 H, L;
#pragma unroll
  for (int j = 0; j < 4; ++j) {
    float x = tile[kq + j][hh];
    f16 xh = (f16)x;
    H[j] = xh;
    L[j] = (f16)((x - (float)xh) * LOSCALE);
  }
  *(f16x4*)&hi[(size_t)(h0 + hh) * DIM + k0 + kq] = H;
  *(f16x4*)&lo[(size_t)(h0 + hh) * DIM + k0 + kq] = L;
}

// ---------------------------------------------------------------------------
// Gate GEMM: partial[ht*2+wn][token] = sum_{h in 64-col slice} relu(A@W1+b1)*W2
// fp16-split MFMA (32x32x16), 128x128 tile, BK=32, dbuf, global_load_lds.
// LDS rows are 128 B: [hi k-slots 0..3 | lo k-slots 0..3] as 8x16B chunks,
// chunk index XOR-swizzled with (row&7) -- T2/G4 pattern, both-sides (rule 21):
// staging pre-swizzles the GLOBAL source address, LDS dest stays linear.
// ---------------------------------------------------------------------------
__global__ __launch_bounds__(256, 2)
void gate_gemm(const f16* __restrict__ Ahi, const f16* __restrict__ Alo,
               const f16* __restrict__ Whi, const f16* __restrict__ Wlo,
               const float* __restrict__ b1, const float* __restrict__ W2,
               float* __restrict__ partial) {
  __shared__ f16 sA[2][BM][64];  // [buf][row][8 chunks x 8 f16]  32 KB
  __shared__ f16 sB[2][BN][64];  //                               32 KB

  // XCD-bijective swizzle (2048 % 8 == 0) + 4x4 supertile for L2 reuse
  const int bid = blockIdx.x;
  const int wg = (bid & 7) * 256 + (bid >> 3);
  const int st = wg >> 4, q5 = wg & 15;
  const int mt = (st >> 3) * 4 + (q5 >> 2);  // 0..63
  const int ht = (st & 7) * 4 + (q5 & 3);    // 0..31
  const int m0 = mt * BM, h0 = ht * BN;

  const int t = threadIdx.x;
  const int lane = t & 63, wid = t >> 6;
  const int wm = wid >> 1, wn = wid & 1;

  f32x16 accM[2][2], accC[2][2];
#pragma unroll
  for (int a = 0; a < 2; ++a)
#pragma unroll
    for (int b = 0; b < 2; ++b)
#pragma unroll
      for (int e = 0; e < 16; ++e) { accM[a][b][e] = 0.f; accC[a][b][e] = 0.f; }

  // staging: 1024 16B chunks per array per kt; chunk sig -> (row=sig>>3, phys p=sig&7)
  // logical chunk q = p ^ (row&7); q<4 -> hi k-slot q, q>=4 -> lo k-slot q-4.
#define STAGE(buf, kt)                                                        \
  {                                                                           \
    const int k0s = (kt) * BKF;                                               \
    _Pragma("unroll") for (int i = 0; i < 4; ++i) {                           \
      int sig = ((wid * 4 + i) << 6) + lane;                                  \
      int r = sig >> 3, p = sig & 7;                                          \
      int q = p ^ (r & 7);                                                    \
      int koff = k0s + (q & 3) * 8;                                           \
      const f16* srcA = (q < 4) ? (Ahi + (size_t)(m0 + r) * DIM + koff)       \
                                : (Alo + (size_t)(m0 + r) * DIM + koff);      \
      const f16* srcB = (q < 4) ? (Whi + (size_t)(h0 + r) * DIM + koff)       \
                                : (Wlo + (size_t)(h0 + r) * DIM + koff);      \
      int ho = ((wid * 4 + i) << 6) * 8;                                      \
      gl16(srcA, &sA[buf][0][0] + ho);                                        \
      gl16(srcB, &sB[buf][0][0] + ho);                                        \
    }                                                                         \
  }

  STAGE(0, 0);
  __syncthreads();

  const int rowl = lane & 31, kb = lane >> 5;

  for (int kt = 0; kt < KITERS; ++kt) {
    const int buf = kt & 1;
    if (kt + 1 < KITERS) STAGE(buf ^ 1, kt + 1);
#pragma unroll
    for (int ks = 0; ks < 2; ++ks) {
      f16x8 ah[2], al[2], bh[2], bl[2];
      const int sl = ks * 2 + kb;   // k-slot 0..3
#pragma unroll
      for (int f = 0; f < 2; ++f) {
        int ra = wm * 64 + f * 32 + rowl;
        int ph = (sl ^ (ra & 7)) * 8;       // swizzled hi chunk (f16 units)
        ah[f] = *(const f16x8*)&sA[buf][ra][ph];
        al[f] = *(const f16x8*)&sA[buf][ra][ph ^ 32];  // lo chunk = hi ^ 4
        int rb = wn * 64 + f * 32 + rowl;
        int pb = (sl ^ (rb & 7)) * 8;
        bh[f] = *(const f16x8*)&sB[buf][rb][pb];
        bl[f] = *(const f16x8*)&sB[buf][rb][pb ^ 32];
      }
#pragma unroll
      for (int fm = 0; fm < 2; ++fm)
#pragma unroll
        for (int fn = 0; fn < 2; ++fn) {
          accM[fm][fn] = __builtin_amdgcn_mfma_f32_32x32x16_f16(
              ah[fm], bh[fn], accM[fm][fn], 0, 0, 0);
          accC[fm][fn] = __builtin_amdgcn_mfma_f32_32x32x16_f16(
              ah[fm], bl[fn], accC[fm][fn], 0, 0, 0);
          accC[fm][fn] = __builtin_amdgcn_mfma_f32_32x32x16_f16(
              al[fm], bh[fn], accC[fm][fn], 0, 0, 0);
        }
    }
    __syncthreads();
  }

  // epilogue: relu(h + b1) * W2, reduce over the 32 h-cols per frag + fn pair
  float b1v[2], w2v[2];
#pragma unroll
  for (int fn = 0; fn < 2; ++fn) {
    int h = h0 + wn * 64 + fn * 32 + rowl;
    b1v[fn] = b1[h];
    w2v[fn] = W2[h];
  }
  float red[2][16];
#pragma unroll
  for (int fm = 0; fm < 2; ++fm)
#pragma unroll
    for (int r = 0; r < 16; ++r) {
      float v0 = accM[fm][0][r] + accC[fm][0][r] * INV_LOSCALE + b1v[0];
      float v1 = accM[fm][1][r] + accC[fm][1][r] * INV_LOSCALE + b1v[1];
      red[fm][r] = fmaxf(v0, 0.f) * w2v[0] + fmaxf(v1, 0.f) * w2v[1];
    }
#pragma unroll
  for (int off = 1; off <= 16; off <<= 1)
#pragma unroll
    for (int fm = 0; fm < 2; ++fm)
#pragma unroll
      for (int r = 0; r < 16; ++r)
        red[fm][r] += __shfl_xor(red[fm][r], off);
  if (rowl == 0) {
    const int hb = ht * 2 + wn;
#pragma unroll
    for (int fm = 0; fm < 2; ++fm)
#pragma unroll
      for (int r = 0; r < 16; ++r) {
        int token = m0 + wm * 64 + fm * 32 + (r & 3) + 8 * (r >> 2) + 4 * kb;
        partial[(size_t)hb * MTOT + token] = red[fm][r];
      }
  }
}

// ---------------------------------------------------------------------------
// Kernel B: logits -> hard boundaries -> scan -> positions/counts/short_mask
// ---------------------------------------------------------------------------
__global__ void boundary_scan(const float* __restrict__ partial,
                              const float* __restrict__ mask,
                              const float* __restrict__ noise,
                              const float* __restrict__ b2,
                              int* __restrict__ bpos, int* __restrict__ counts,
                              int* __restrict__ lengths,
                              float* __restrict__ shortmask) {
  const int b = blockIdx.x;
  const int t = threadIdx.x;
  __shared__ float hardS[SEQ];
  __shared__ float red[256];
  const float bias2 = b2[0];

  float msum = 0.f;
  for (int s = t; s < SEQ; s += 256) {
    float lg = bias2;
#pragma unroll
    for (int h = 0; h < NHB; ++h) lg += partial[(size_t)h * MTOT + b * SEQ + s];
    float u = noise[b * SEQ + s];
    float lgt = logf(u) - log1pf(-u);
    float m = mask[b * SEQ + s];
    float hard = ((lg + lgt) > 0.f) ? 1.f : 0.f;
    hardS[s] = hard * m;
    msum += m;
  }
  red[t] = msum;
  __syncthreads();
  for (int off = 128; off > 0; off >>= 1) {
    if (t < off) red[t] += red[t + off];
    __syncthreads();
  }
  int L = (int)(red[0] + 0.5f);
  __syncthreads();
  if (t == 0) {
    if (L < SEQ) hardS[L - 1] = fmaxf(hardS[L - 1], 1.f);
    lengths[b] = L;
  }
  __syncthreads();

  float loc[8];
  float run = 0.f;
#pragma unroll
  for (int i = 0; i < 8; ++i) { loc[i] = hardS[t * 8 + i]; run += loc[i]; }
  red[t] = run;
  __syncthreads();
  for (int off = 1; off < 256; off <<= 1) {
    float v = (t >= off) ? red[t - off] : 0.f;
    __syncthreads();
    red[t] += v;
    __syncthreads();
  }
  float base = red[t] - run;
  int cnt = (int)(red[255] + 0.5f);

  float pre = base;
#pragma unroll
  for (int i = 0; i < 8; ++i) {
    if (loc[i] > 0.5f) {
      int rank = (int)(pre + 0.5f);
      bpos[b * SEQ + rank] = t * 8 + i;
    }
    pre += loc[i];
  }
  if (t == 0) counts[b] = cnt;
  for (int s = t; s < SEQ; s += 256)
    shortmask[b * SEQ + s] = (s < cnt) ? 1.f : 0.f;
}

// ---------------------------------------------------------------------------
// Pooling kernels (unchanged)
// ---------------------------------------------------------------------------
__global__ void pool_seg(const float* __restrict__ hidden,
                         const int* __restrict__ bpos,
                         const int* __restrict__ counts,
                         float* __restrict__ pooled) {
  const int g = blockIdx.x, b = blockIdx.y;
  const int t = threadIdx.x;
  const int cnt = counts[b];
  float4 acc = {0.f, 0.f, 0.f, 0.f};
  float* outp = pooled + ((size_t)(b * SEQ + g)) * DIM + t * 4;
  if (g > cnt) { *(float4*)outp = acc; return; }
  if (g == cnt) return;
  int start = (g == 0) ? 0 : bpos[b * SEQ + g - 1] + 1;
  int end = bpos[b * SEQ + g] + 1;
  const float* hb = hidden + ((size_t)b * SEQ) * DIM + t * 4;
  for (int l = start; l < end; ++l) {
    float4 v = *(const float4*)(hb + (size_t)l * DIM);
    acc.x += v.x; acc.y += v.y; acc.z += v.z; acc.w += v.w;
  }
  float inv = 1.f / ((float)(end - start) + EPSF);
  acc.x *= inv; acc.y *= inv; acc.z *= inv; acc.w *= inv;
  *(float4*)outp = acc;
}

__global__ void pool_tail_partial(const float* __restrict__ hidden,
                                  const int* __restrict__ bpos,
                                  const int* __restrict__ counts,
                                  float* __restrict__ tailpart) {
  const int c = blockIdx.x;
  const int b = blockIdx.y;
  const int t = threadIdx.x;
  int cnt = counts[b];
  int start = (cnt == 0) ? 0 : bpos[b * SEQ + cnt - 1] + 1;
  int n = SEQ - start;
  int clen = (n + 15) / 16;
  int s0 = start + c * clen;
  int s1 = s0 + clen; if (s1 > SEQ) s1 = SEQ;
  float4 acc = {0.f, 0.f, 0.f, 0.f};
  const float* hb = hidden + ((size_t)b * SEQ) * DIM + t * 4;
  for (int l = s0; l < s1; ++l) {
    float4 v = *(const float4*)(hb + (size_t)l * DIM);
    acc.x += v.x; acc.y += v.y; acc.z += v.z; acc.w += v.w;
  }
  *(float4*)(tailpart + ((size_t)(b * 16 + c)) * DIM + t * 4) = acc;
}

__global__ void pool_tail_final(const int* __restrict__ bpos,
                                const int* __restrict__ counts,
                                const float* __restrict__ tailpart,
                                float* __restrict__ pooled) {
  const int b = blockIdx.x;
  const int t = threadIdx.x;
  int cnt = counts[b];
  if (cnt >= SEQ) return;
  int start = (cnt == 0) ? 0 : bpos[b * SEQ + cnt - 1] + 1;
  float4 acc = {0.f, 0.f, 0.f, 0.f};
  for (int c = 0; c < 16; ++c) {
    float4 v = *(const float4*)(tailpart + ((size_t)(b * 16 + c)) * DIM + t * 4);
    acc.x += v.x; acc.y += v.y; acc.z += v.z; acc.w += v.w;
  }
  float inv = 1.f / ((float)(SEQ - start) + EPSF);
  acc.x *= inv; acc.y *= inv; acc.z *= inv; acc.w *= inv;
  *(float4*)(pooled + ((size_t)(b * SEQ + cnt)) * DIM + t * 4) = acc;
}

__global__ void loss_kernel(const int* __restrict__ counts,
                            const int* __restrict__ lengths,
                            float* __restrict__ outScalars) {
  if (threadIdx.x != 0 || blockIdx.x != 0) return;
  double num_b = 0.0, total = 0.0;
  for (int b = 0; b < BSZ; ++b) { num_b += (double)counts[b]; total += (double)lengths[b]; }
  double lp = lgamma(total + 1.0) - lgamma(num_b + 1.0) - lgamma(total - num_b + 1.0)
            + num_b * log(0.2) + (total - num_b) * log(0.8);
  outScalars[0] = (float)(-lp / total);
  outScalars[1] = (float)num_b;
  outScalars[2] = (float)total;
}

// ---------------------------------------------------------------------------
extern "C" void kernel_launch(void* const* d_in, const int* in_sizes, int n_in,
                              void* d_out, int out_size, void* d_ws, size_t ws_size,
                              hipStream_t stream) {
  const float* hidden = (const float*)d_in[0];
  const float* mask   = (const float*)d_in[1];
  const float* noise  = (const float*)d_in[2];
  const float* W1     = (const float*)d_in[3];
  const float* b1     = (const float*)d_in[4];
  const float* W2     = (const float*)d_in[5];
  const float* b2     = (const float*)d_in[6];

  float* out = (float*)d_out;
  float* pooled = out;
  float* scalars = out + (size_t)BSZ * SEQ * DIM;
  float* shortmask = scalars + 3;

  char* ws = (char*)d_ws;
  size_t off = 0;
  float* partial = (float*)(ws + off); off += (size_t)NHB * MTOT * sizeof(float); // 2 MB
  f16* Ahi = (f16*)(ws + off); off += (size_t)MTOT * DIM * sizeof(f16);           // 16 MB
  f16* Alo = (f16*)(ws + off); off += (size_t)MTOT * DIM * sizeof(f16);           // 16 MB
  f16* Whi = (f16*)(ws + off); off += (size_t)HID * DIM * sizeof(f16);            // 8 MB
  f16* Wlo = (f16*)(ws + off); off += (size_t)HID * DIM * sizeof(f16);            // 8 MB
  int* bpos = (int*)(ws + off); off += (size_t)BSZ * SEQ * sizeof(int);
  int* counts = (int*)(ws + off); off += 16 * sizeof(int);
  int* lengths = (int*)(ws + off); off += 16 * sizeof(int);
  off = (off + 255) & ~(size_t)255;
  float* tailpart = (float*)(ws + off);                                           // 256 KB

  split_a<<<MTOT * DIM / 4 / 256, 256, 0, stream>>>(hidden, Ahi, Alo);
  split_w1t<<<dim3(DIM / 32, HID / 32), 256, 0, stream>>>(W1, Whi, Wlo);
  gate_gemm<<<(MTOT / BM) * (HID / BN), 256, 0, stream>>>(Ahi, Alo, Whi, Wlo,
                                                          b1, W2, partial);
  boundary_scan<<<BSZ, 256, 0, stream>>>(partial, mask, noise, b2,
                                         bpos, counts, lengths, shortmask);
  pool_tail_partial<<<dim3(16, BSZ), 256, 0, stream>>>(hidden, bpos, counts, tailpart);
  pool_seg<<<dim3(SEQ, BSZ), 256, 0, stream>>>(hidden, bpos, counts, pooled);
  pool_tail_final<<<BSZ, 256, 0, stream>>>(bpos, counts, tailpart, pooled);
  loss_kernel<<<1, 1, 0, stream>>>(counts, lengths, scalars);
}